// Round 6
// baseline (282.287 us; speedup 1.0000x reference)
//
#include <hip/hip_runtime.h>
#include <math.h>

#define B_ 2
#define S_ 2048
#define C_ 1024
#define H_ 16
#define D_ 64

typedef __bf16 bf16_t;
typedef __attribute__((ext_vector_type(8))) __bf16 bf16x8;
typedef __attribute__((ext_vector_type(4))) __bf16 bf16x4;
typedef __attribute__((ext_vector_type(4))) float f32x4;

__device__ __forceinline__ void gload16(const void* g, void* l) {
    __builtin_amdgcn_global_load_lds(
        (const __attribute__((address_space(1))) unsigned int*)g,
        (__attribute__((address_space(3))) unsigned int*)l, 16, 0, 0);
}

__device__ __forceinline__ float tanh_fast(float z) {
    z = fminf(fmaxf(z, -12.f), 12.f);
    float e = __expf(2.f * z);
    return 1.f - __fdividef(2.f, e + 1.f);
}

__device__ __forceinline__ float mish_f(float x) {
    float sp = (x > 15.f) ? x : log1pf(__expf(x));
    return x * tanh_fast(sp);
}

// tanh(t*w+b) with 2/ln2 pre-folded into w2,b2: 1 - 2*rcp(exp2(t*w2+b2)+1)
__device__ __forceinline__ float tanh_folded(float t, float w2, float b2) {
    float e = __builtin_amdgcn_exp2f(fmaf(t, w2, b2));
    float r = __builtin_amdgcn_rcpf(e + 1.f);
    return fmaf(-2.f, r, 1.f);
}

__device__ __forceinline__ bf16x8 tanh8(float4 u, float4 v, float w2, float b2) {
    bf16x8 o;
    o[0] = (bf16_t)tanh_folded(u.x, w2, b2);
    o[1] = (bf16_t)tanh_folded(u.y, w2, b2);
    o[2] = (bf16_t)tanh_folded(u.z, w2, b2);
    o[3] = (bf16_t)tanh_folded(u.w, w2, b2);
    o[4] = (bf16_t)tanh_folded(v.x, w2, b2);
    o[5] = (bf16_t)tanh_folded(v.y, w2, b2);
    o[6] = (bf16_t)tanh_folded(v.z, w2, b2);
    o[7] = (bf16_t)tanh_folded(v.w, w2, b2);
    return o;
}

// -------------------------------------------------------------------------
// Merged preprocessing: blocks 0..4095 = fp32->bf16 of y,x;
// blocks 4096..4863 = transpose-convert wq/wk/wv -> [N][K] bf16.
// -------------------------------------------------------------------------
__global__ __launch_bounds__(256) void prep_kernel(
    const float* __restrict__ y, bf16_t* __restrict__ ybf,
    const float* __restrict__ x, bf16_t* __restrict__ xbf,
    const float* __restrict__ wq, const float* __restrict__ wk,
    const float* __restrict__ wv,
    bf16_t* __restrict__ wqt, bf16_t* __restrict__ wkt,
    bf16_t* __restrict__ wvt)
{
    __shared__ float ts[64][65];
    const int bid = blockIdx.x;
    const int t = threadIdx.x;
    if (bid < 4096) {
        const float* in = (bid < 2048) ? y : x;
        bf16_t* out = (bid < 2048) ? ybf : xbf;
        size_t i = ((size_t)(bid & 2047) * 256 + t) * 8;
        float4 u = *(const float4*)&in[i];
        float4 v = *(const float4*)&in[i + 4];
        bf16x8 o;
        o[0] = (bf16_t)u.x; o[1] = (bf16_t)u.y; o[2] = (bf16_t)u.z; o[3] = (bf16_t)u.w;
        o[4] = (bf16_t)v.x; o[5] = (bf16_t)v.y; o[6] = (bf16_t)v.z; o[7] = (bf16_t)v.w;
        *(bf16x8*)&out[i] = o;
    } else {
        const int r3 = bid - 4096;           // 0..767
        const int z = r3 >> 8;
        const int rem = r3 & 255;
        const int k0 = (rem >> 4) * 64, n0 = (rem & 15) * 64;
        const float* in = z == 0 ? wq : (z == 1 ? wk : wv);
        bf16_t* out = z == 0 ? wqt : (z == 1 ? wkt : wvt);
        const int r = t >> 2, c0 = (t & 3) * 16;
        #pragma unroll
        for (int j = 0; j < 16; j += 4) {
            float4 v = *(const float4*)&in[(size_t)(k0 + r) * C_ + n0 + c0 + j];
            ts[c0 + j + 0][r] = v.x; ts[c0 + j + 1][r] = v.y;
            ts[c0 + j + 2][r] = v.z; ts[c0 + j + 3][r] = v.w;
        }
        __syncthreads();
        #pragma unroll
        for (int g = 0; g < 2; ++g) {
            bf16x8 o;
            #pragma unroll
            for (int e = 0; e < 8; ++e) o[e] = (bf16_t)ts[r][c0 + g * 8 + e];
            *(bf16x8*)&out[(size_t)(n0 + r) * C_ + k0 + c0 + g * 8] = o;
        }
    }
}

// -------------------------------------------------------------------------
// Fused QKV projection. z=0: y@wq -> Qt (transposed), z=1: x@wk -> Kb,
// z=2: y@wv -> Vt (transposed). 128x128 tile, BK=32.
// -------------------------------------------------------------------------
__global__ __launch_bounds__(256) void qkv_proj(
    const bf16_t* __restrict__ ybf, const bf16_t* __restrict__ xbf,
    const bf16_t* __restrict__ wqt, const bf16_t* __restrict__ wkt,
    const bf16_t* __restrict__ wvt,
    const float* __restrict__ bq, const float* __restrict__ bk,
    const float* __restrict__ bv,
    bf16_t* __restrict__ Qt, bf16_t* __restrict__ Kb, bf16_t* __restrict__ Vt)
{
    const int z = blockIdx.z;
    const bf16_t* A  = (z == 1) ? xbf : ybf;
    const bf16_t* Bt = (z == 0) ? wqt : (z == 1) ? wkt : wvt;
    const float* bias = (z == 0) ? bq : (z == 1) ? bk : bv;
    const int K = C_;

    __shared__ bf16_t As[128 * 32];
    __shared__ bf16_t Bs[128 * 32];

    const int t = threadIdx.x;
    const int w = t >> 6, lane = t & 63;
    const int wm = (w >> 1) * 64, wn = (w & 1) * 64;
    const int l15 = lane & 15, l4 = lane >> 4;
    const int row0 = blockIdx.y * 128, col0 = blockIdx.x * 128;

    const int sr = t >> 2, sk = (t & 3) * 8;
    const bf16_t* gA = A + (size_t)(row0 + sr) * K + sk;
    const bf16_t* gB = Bt + (size_t)(col0 + sr) * K + sk;
    bf16_t* lA = As + (t & ~63) * 8;
    bf16_t* lB = Bs + (t & ~63) * 8;

    f32x4 acc[4][4] = {};

    for (int k0 = 0; k0 < K; k0 += 32) {
        __syncthreads();
        gload16(gA + k0, lA);
        gload16(gA + k0 + (size_t)64 * K, lA + 2048);
        gload16(gB + k0, lB);
        gload16(gB + k0 + (size_t)64 * K, lB + 2048);
        __syncthreads();
        bf16x8 a[4], b[4];
        #pragma unroll
        for (int i = 0; i < 4; ++i)
            a[i] = *(const bf16x8*)&As[(wm + i * 16 + l15) * 32 + l4 * 8];
        #pragma unroll
        for (int j = 0; j < 4; ++j)
            b[j] = *(const bf16x8*)&Bs[(wn + j * 16 + l15) * 32 + l4 * 8];
        #pragma unroll
        for (int i = 0; i < 4; ++i)
            #pragma unroll
            for (int j = 0; j < 4; ++j)
                acc[i][j] = __builtin_amdgcn_mfma_f32_16x16x32_bf16(
                    a[i], b[j], acc[i][j], 0, 0, 0);
    }

    if (z != 1) {
        bf16_t* To = (z == 0) ? Qt : Vt;
        #pragma unroll
        for (int i = 0; i < 4; ++i) {
            int mb = row0 + wm + i * 16 + l4 * 4;
            int b2 = mb >> 11, s = mb & 2047;
            #pragma unroll
            for (int j = 0; j < 4; ++j) {
                int c = col0 + wn + j * 16 + l15;
                float bv2 = bias[c];
                bf16x4 o;
                #pragma unroll
                for (int r = 0; r < 4; ++r) o[r] = (bf16_t)(acc[i][j][r] + bv2);
                *(bf16x4*)&To[((size_t)b2 * C_ + c) * S_ + s] = o;
            }
        }
    } else {
        #pragma unroll
        for (int i = 0; i < 4; ++i)
            #pragma unroll
            for (int j = 0; j < 4; ++j) {
                int c = col0 + wn + j * 16 + l15;
                float bv2 = bias[c];
                #pragma unroll
                for (int r = 0; r < 4; ++r) {
                    int m = row0 + wm + i * 16 + l4 * 4 + r;
                    Kb[(size_t)m * C_ + c] = (bf16_t)(acc[i][j][r] + bv2);
                }
            }
    }
}

// -------------------------------------------------------------------------
// FUSED cv + qtcv, TWO HEADS per block (t_mat tile loaded once, used for
// both heads' tanh -> halves t_mat flow & load-issue vs one-head version).
//   cv_g(q,d) = sum_s tanh(t*wc_g+bc_g) * V_g[s,d]   g in {h0,h1}
//   then M[bh_g,d',d] += Qt_g[d',q] * cv_g(q,d)      (MFMA epilogue, atomics)
// grid (S/128=16, P=4, B*H/2=16) = 1024 blocks = 4/CU.  LDS 32 KB.
// As wave-private; Bs double-buffered; single barrier per iter.
// -------------------------------------------------------------------------
__global__ __launch_bounds__(256) void cv_qtcv_fused(
    const float* __restrict__ t_mat, const bf16_t* __restrict__ Vt,
    const bf16_t* __restrict__ Qt,
    const float* __restrict__ wc, const float* __restrict__ bc,
    float* __restrict__ Mm)
{
    const int bhp = blockIdx.z;                 // 0..15
    const int b = bhp >> 3, hp = bhp & 7;
    const int h0 = hp * 2, h1 = h0 + 1;
    const int q0 = blockIdx.x * 128;
    const int p = blockIdx.y;
    const int t = threadIdx.x;
    const int w = t >> 6, lane = t & 63;
    const int l15 = lane & 15, l4 = lane >> 4;

    __shared__ bf16_t smem[16384];       // 32 KB
    bf16_t* As0 = smem;                  // 128*32 (8 KB)
    bf16_t* As1 = smem + 4096;           // 128*32 (8 KB)
    bf16_t* Bsb = smem + 8192;           // 4 x 64*32: [head*2+buf] (16 KB)
    bf16_t* cvs = smem;                  // epilogue: [c][64][40] (20 KB)

    const float LOG2E2 = 2.8853900817779268f;  // 2/ln2
    const float w20 = wc[h0] * LOG2E2, b20 = bc[h0] * LOG2E2;
    const float w21 = wc[h1] * LOG2E2, b21 = bc[h1] * LOG2E2;
    const float* tb = t_mat + (size_t)b * S_ * S_ + (size_t)q0 * S_;
    const bf16_t* Vb0 = Vt + ((size_t)b * C_ + h0 * 64) * S_;
    const bf16_t* Vb1 = Vb0 + (size_t)64 * S_;

    const int rr = t >> 1, sp = (t & 1) * 16;   // A: row (wave-aligned), s-off
    const int vd = t >> 2, vse = (t & 3) * 8;   // B staging
    const int lBoff = (t & ~63) * 8;            // per-wave Bs slice

    f32x4 acc0[2][4] = {};
    f32x4 acc1[2][4] = {};

    const int s_beg = p * 512, s_end = s_beg + 512;
    const float* trow = tb + (size_t)rr * S_ + sp;

    // prime the t_mat prefetch registers
    float4 v0 = *(const float4*)&trow[s_beg];
    float4 v1 = *(const float4*)&trow[s_beg + 4];
    float4 v2 = *(const float4*)&trow[s_beg + 8];
    float4 v3 = *(const float4*)&trow[s_beg + 12];

    int buf = 0;
    for (int s0 = s_beg; s0 < s_end; s0 += 32, buf ^= 1) {
        // stage both heads' V chunks early (async DMA)
        gload16(Vb0 + (size_t)vd * S_ + s0 + vse, Bsb + (0 + buf) * 2048 + lBoff);
        gload16(Vb1 + (size_t)vd * S_ + s0 + vse, Bsb + (2 + buf) * 2048 + lBoff);
        // tanh for both heads from the same register tile
        bf16x8 p00 = tanh8(v0, v1, w20, b20);
        bf16x8 p01 = tanh8(v2, v3, w20, b20);
        bf16x8 p10 = tanh8(v0, v1, w21, b21);
        bf16x8 p11 = tanh8(v2, v3, w21, b21);
        *(bf16x8*)&As0[rr * 32 + sp]     = p00;
        *(bf16x8*)&As0[rr * 32 + sp + 8] = p01;
        *(bf16x8*)&As1[rr * 32 + sp]     = p10;
        *(bf16x8*)&As1[rr * 32 + sp + 8] = p11;
        __syncthreads();   // drains vmcnt (gload) + lgkmcnt for all waves
        // prefetch next iter's t_mat into regs
        if (s0 + 32 < s_end) {
            const float* nrow = &trow[s0 + 32];
            v0 = *(const float4*)&nrow[0];
            v1 = *(const float4*)&nrow[4];
            v2 = *(const float4*)&nrow[8];
            v3 = *(const float4*)&nrow[12];
        }
        bf16x8 a0 = *(const bf16x8*)&As0[(w * 32 + l15) * 32 + l4 * 8];
        bf16x8 a1 = *(const bf16x8*)&As0[(w * 32 + 16 + l15) * 32 + l4 * 8];
        #pragma unroll
        for (int j = 0; j < 4; ++j) {
            bf16x8 bb = *(const bf16x8*)&Bsb[(0 + buf) * 2048 + (j * 16 + l15) * 32 + l4 * 8];
            acc0[0][j] = __builtin_amdgcn_mfma_f32_16x16x32_bf16(a0, bb, acc0[0][j], 0, 0, 0);
            acc0[1][j] = __builtin_amdgcn_mfma_f32_16x16x32_bf16(a1, bb, acc0[1][j], 0, 0, 0);
        }
        bf16x8 c0 = *(const bf16x8*)&As1[(w * 32 + l15) * 32 + l4 * 8];
        bf16x8 c1 = *(const bf16x8*)&As1[(w * 32 + 16 + l15) * 32 + l4 * 8];
        #pragma unroll
        for (int j = 0; j < 4; ++j) {
            bf16x8 bb = *(const bf16x8*)&Bsb[(2 + buf) * 2048 + (j * 16 + l15) * 32 + l4 * 8];
            acc1[0][j] = __builtin_amdgcn_mfma_f32_16x16x32_bf16(c0, bb, acc1[0][j], 0, 0, 0);
            acc1[1][j] = __builtin_amdgcn_mfma_f32_16x16x32_bf16(c1, bb, acc1[1][j], 0, 0, 0);
        }
    }

    // ---- epilogue (per head): M[d',d] += Qt[d',q] * cv(q,d) over q-tile
    #pragma unroll
    for (int g = 0; g < 2; ++g) {
        const int h = g ? h1 : h0;
        __syncthreads();   // previous smem reads done; safe to overwrite cvs
        #pragma unroll
        for (int i = 0; i < 2; ++i)
            #pragma unroll
            for (int j = 0; j < 4; ++j) {
                int d = j * 16 + l15;
                bf16x4 o;
                #pragma unroll
                for (int r = 0; r < 4; ++r)
                    o[r] = (bf16_t)(g ? acc1[i][j][r] : acc0[i][j][r]);
                *(bf16x4*)&cvs[(size_t)w * 2560 + d * 40 + i * 16 + l4 * 4] = o;
            }
        __syncthreads();

        const bf16_t* Qrow = Qt + ((size_t)b * C_ + h * 64 + w * 16 + l15) * S_
                             + q0 + l4 * 8;
        f32x4 macc[4] = {};
        #pragma unroll
        for (int c = 0; c < 4; ++c) {
            bf16x8 a = *(const bf16x8*)&Qrow[c * 32];
            #pragma unroll
            for (int j = 0; j < 4; ++j) {
                bf16x8 bb = *(const bf16x8*)&cvs[(size_t)c * 2560 +
                                                 (j * 16 + l15) * 40 + l4 * 8];
                macc[j] = __builtin_amdgcn_mfma_f32_16x16x32_bf16(a, bb, macc[j], 0, 0, 0);
            }
        }

        float* mp = Mm + (size_t)(b * H_ + h) * 64 * 64;
        #pragma unroll
        for (int j = 0; j < 4; ++j)
            #pragma unroll
            for (int r = 0; r < 4; ++r)
                atomicAdd(&mp[(size_t)(w * 16 + l4 * 4 + r) * 64 + j * 16 + l15],
                          macc[j][r]);
    }
}

// -------------------------------------------------------------------------
// Wefft[b, co, h*64+d'] = (1/8) * sum_d M[bh,d',d] * wf[h*64+d, co]  (bf16)
// -------------------------------------------------------------------------
__global__ __launch_bounds__(256) void weff_kernel(
    const float* __restrict__ Mm, const float* __restrict__ wf,
    bf16_t* __restrict__ Wefft)
{
    const int b = blockIdx.z, h = blockIdx.y;
    const int co0 = blockIdx.x * 64;
    const int t = threadIdx.x;
    const int tx = t & 15, ty = t >> 4;

    __shared__ float Ms[64][64];
    __shared__ float Ws[64][64];

    const float* Mb = Mm + (size_t)(b * H_ + h) * 64 * 64;

    const int r  = t >> 2;
    const int c4 = (t & 3) << 2;

    #pragma unroll
    for (int rep = 0; rep < 4; ++rep) {
        int col = c4 + rep * 16;
        float4 m4 = *(const float4*)&Mb[(size_t)r * 64 + col];
        Ms[col + 0][r] = m4.x; Ms[col + 1][r] = m4.y;
        Ms[col + 2][r] = m4.z; Ms[col + 3][r] = m4.w;
        float4 w4 = *(const float4*)&wf[(size_t)(h * 64 + r) * C_ + co0 + col];
        *(float4*)&Ws[r][col] = w4;
    }
    __syncthreads();

    float acc[4][4] = {};
    #pragma unroll
    for (int kk = 0; kk < 64; ++kk) {
        float av[4], bv2[4];
        *(float4*)&av[0] = *(const float4*)&Ms[kk][ty * 4];
        *(float4*)&bv2[0] = *(const float4*)&Ws[kk][tx * 4];
        #pragma unroll
        for (int i = 0; i < 4; ++i)
            #pragma unroll
            for (int j = 0; j < 4; ++j)
                acc[i][j] = fmaf(av[i], bv2[j], acc[i][j]);
    }

    bf16_t* wp = Wefft + (size_t)b * C_ * C_;
    #pragma unroll
    for (int i = 0; i < 4; ++i)
        #pragma unroll
        for (int j = 0; j < 4; ++j)
            wp[(size_t)(co0 + tx * 4 + j) * C_ + h * 64 + ty * 4 + i] =
                (bf16_t)(acc[i][j] * 0.125f);  // fold 1/sqrt(D)=1/8
}

// -------------------------------------------------------------------------
// out = mish(Kb[b] @ Wefft[b]^T + bf), fp32 out. 128x64 tiles,
// grid (16, 16, 2) = 512 blocks (2/CU).
// -------------------------------------------------------------------------
__global__ __launch_bounds__(256) void final_gemm(
    const bf16_t* __restrict__ Kb, const bf16_t* __restrict__ Weft,
    const float* __restrict__ bias, float* __restrict__ out)
{
    const int z = blockIdx.z;
    const bf16_t* A  = Kb + (size_t)z * S_ * C_;
    const bf16_t* Bt = Weft + (size_t)z * C_ * C_;
    float* Co = out + (size_t)z * S_ * C_;
    const int K = C_;

    __shared__ bf16_t As[128 * 32];
    __shared__ bf16_t Bs[64 * 32];

    const int t = threadIdx.x;
    const int w = t >> 6, lane = t & 63;
    const int l15 = lane & 15, l4 = lane >> 4;
    const int row0 = blockIdx.y * 128, col0 = blockIdx.x * 64;

    const int sr = t >> 2, sk = (t & 3) * 8;
    const bf16_t* gA = A + (size_t)(row0 + sr) * K + sk;
    const bf16_t* gB = Bt + (size_t)(col0 + sr) * K + sk;
    bf16_t* lA = As + (t & ~63) * 8;
    bf16_t* lB = Bs + (t & ~63) * 8;

    f32x4 acc[2][4] = {};

    for (int k0 = 0; k0 < K; k0 += 32) {
        __syncthreads();
        gload16(gA + k0, lA);
        gload16(gA + k0 + (size_t)64 * K, lA + 2048);
        gload16(gB + k0, lB);
        __syncthreads();
        bf16x8 a0 = *(const bf16x8*)&As[(w * 32 + l15) * 32 + l4 * 8];
        bf16x8 a1 = *(const bf16x8*)&As[(w * 32 + 16 + l15) * 32 + l4 * 8];
        #pragma unroll
        for (int j = 0; j < 4; ++j) {
            bf16x8 bb = *(const bf16x8*)&Bs[(j * 16 + l15) * 32 + l4 * 8];
            acc[0][j] = __builtin_amdgcn_mfma_f32_16x16x32_bf16(a0, bb, acc[0][j], 0, 0, 0);
            acc[1][j] = __builtin_amdgcn_mfma_f32_16x16x32_bf16(a1, bb, acc[1][j], 0, 0, 0);
        }
    }

    #pragma unroll
    for (int i = 0; i < 2; ++i)
        #pragma unroll
        for (int j = 0; j < 4; ++j) {
            int c = col0 + j * 16 + l15;
            float bv2 = bias[c];
            #pragma unroll
            for (int r = 0; r < 4; ++r) {
                int m = row0 + w * 32 + i * 16 + l4 * 4 + r;
                Co[(size_t)m * C_ + c] = mish_f(acc[i][j][r] + bv2);
            }
        }
}

// -------------------------------------------------------------------------
extern "C" void kernel_launch(void* const* d_in, const int* in_sizes, int n_in,
                              void* d_out, int out_size, void* d_ws, size_t ws_size,
                              hipStream_t stream) {
    const float* x     = (const float*)d_in[0];
    const float* y     = (const float*)d_in[1];
    const float* t_mat = (const float*)d_in[2];
    const float* wq    = (const float*)d_in[3];
    const float* bq    = (const float*)d_in[4];
    const float* wk    = (const float*)d_in[5];
    const float* bk    = (const float*)d_in[6];
    const float* wv    = (const float*)d_in[7];
    const float* bv    = (const float*)d_in[8];
    const float* wc    = (const float*)d_in[9];
    const float* bc    = (const float*)d_in[10];
    const float* wf    = (const float*)d_in[11];
    const float* bf    = (const float*)d_in[12];
    float* out = (float*)d_out;

    // workspace layout (byte offsets)
    char* base = (char*)d_ws;
    bf16_t* Qt   = (bf16_t*)(base + 0);          //  8 MiB  [b][c][s]
    bf16_t* Kb   = (bf16_t*)(base + 8388608);    //  8 MiB  [b*s][c]
    bf16_t* Vt   = (bf16_t*)(base + 16777216);   //  8 MiB  [b][c][s]
    float*  Mm   = (float*) (base + 25165824);   //  0.5 MiB
    bf16_t* Weft = (bf16_t*)(base + 25690112);   //  4 MiB  [b][co][cin]
    bf16_t* ybf  = (bf16_t*)(base + 29884416);   //  8 MiB
    bf16_t* xbf  = (bf16_t*)(base + 38273024);   //  8 MiB
    bf16_t* wqt  = (bf16_t*)(base + 46661632);   //  2 MiB
    bf16_t* wkt  = (bf16_t*)(base + 48758784);   //  2 MiB
    bf16_t* wvt  = (bf16_t*)(base + 50855936);   //  2 MiB

    hipMemsetAsync(Mm, 0, (size_t)B_ * H_ * 64 * 64 * sizeof(float), stream);

    dim3 blk(256);

    // merged conversions + weight transposes (4864 blocks)
    prep_kernel<<<dim3(4864), blk, 0, stream>>>(
        y, ybf, x, xbf, wq, wk, wv, wqt, wkt, wvt);

    // fused QKV projections (768 blocks)
    qkv_proj<<<dim3(C_ / 128, (B_ * S_) / 128, 3), blk, 0, stream>>>(
        ybf, xbf, wqt, wkt, wvt, bq, bk, bv, Qt, Kb, Vt);

    // fused cv + M-accumulation, 2 heads/block (1024 blocks)
    cv_qtcv_fused<<<dim3(S_ / 128, 4, B_ * H_ / 2), blk, 0, stream>>>(
        t_mat, Vt, Qt, wc, bc, Mm);

    // Weff^T (bf16), 1/8 folded
    weff_kernel<<<dim3(C_ / 64, H_, B_), blk, 0, stream>>>(Mm, wf, Weft);

    // out = mish(K @ Weff + bf), 512 blocks
    final_gemm<<<dim3(C_ / 64, S_ / 128, B_), blk, 0, stream>>>(
        Kb, Weft, bf, out);
}